// Round 5
// baseline (303.486 us; speedup 1.0000x reference)
//
#include <hip/hip_runtime.h>

#define NN 2048   // factor dim
#define KK 16     // nonzeros per row

// ---------------------------------------------------------------------------
// Stage A: compose W0 @ W1 into per-column coefficient table.
// W01[c1][i] = coefficient of x[s1' + 128*i] in y1[c1], s1' = (c1-1) mod 128.
// ---------------------------------------------------------------------------
__global__ __launch_bounds__(256) void sfd_compose01(const float* __restrict__ v0,
                                                     const float* __restrict__ v1,
                                                     float* __restrict__ w01) {
  int tid = blockIdx.x * 256 + threadIdx.x;   // 32768 threads: (c1, i)
  int c1 = tid >> 4;
  int i  = tid & 15;
  int cm = (c1 + NN - 1) & (NN - 1);          // (c1 - 1) mod N
  int s1 = cm & 127;
  int t1 = cm >> 7;
  int rx = s1 + (i << 7);
  float acc = 0.f;
#pragma unroll
  for (int k1 = 0; k1 < 16; ++k1) {
    int r0 = (cm - (k1 << 7)) & (NN - 1);
    int k0 = (t1 - k1 - i) & 15;
    acc = fmaf(v1[r0 * 16 + k1], v0[rx * 16 + k0], acc);
  }
  w01[c1 * 16 + i] = acc;
}

// ---------------------------------------------------------------------------
// Stage B: compose (W0@W1) @ W2, fold in scaling, store residue-major:
// mcl[((s*16 + j)*16) + i]  for col c = s + 128*j, coefficient of
// x[((c-3) mod 128) + 128*i]  (i is the ABSOLUTE 128-block index).
// ---------------------------------------------------------------------------
__global__ __launch_bounds__(256) void sfd_compose012(const float* __restrict__ v2,
                                                      const float* __restrict__ w01,
                                                      const float* __restrict__ scaling,
                                                      float* __restrict__ mcl) {
  int tid = blockIdx.x * 256 + threadIdx.x;   // 32768 threads: (c, i)
  int c = tid >> 4;
  int i = tid & 15;
  float acc = 0.f;
#pragma unroll
  for (int k2 = 0; k2 < 16; ++k2) {
    int r1 = (c + NN - 2 - (k2 << 7)) & (NN - 1);
    acc = fmaf(v2[r1 * 16 + k2], w01[r1 * 16 + i], acc);
  }
  int s = c & 127;
  int j = c >> 7;
  mcl[(s * 16 + j) * 16 + i] = acc * scaling[0];
}

// ---------------------------------------------------------------------------
// Apply, LDS-free: out[b][c] = relu(sum_i mcl[c][i]*x[b][(c-3)%128+128i] + bias[c])
// Block: strip of 32 residues x 32 batch rows; grid (4, 512) = 2048 blocks.
// Thread (u=t&31, jp=t>>5) owns 2 cols c = S0+u+128*(2jp+{0,1}).
// R4 bugfix: res = (w0+u) & 127 is taken FIRST, so off[i] = res + 128*i
// (max 2047, no wrap) is exactly i-aligned with the mcl coefficient index —
// the previous version's (w0+u+128i) mod 2048 rotated slots by 1 for
// threads with w0+u >= 128 (the R1/R2 `shift` that R4 wrongly dropped).
// Per row: 16 direct global gathers (lanes u and u+32 read identical
// addresses -> broadcast; the 8 waves' repeats hit L1: 2 KB/row window).
// Register double-buffer keeps next row's loads in flight during current
// row's FMAs. NO LDS, NO barriers -> no staging/compute phase convoy.
// ---------------------------------------------------------------------------
__global__ __launch_bounds__(256, 4) void sfd_apply(const float* __restrict__ x,
                                                    const float* __restrict__ mcl,
                                                    const float* __restrict__ bias,
                                                    float* __restrict__ out) {
  const int S0 = blockIdx.x << 5;             // strip base residue: 0,32,64,96
  const int b0 = blockIdx.y << 5;             // 32 batch rows per block
  const int t = threadIdx.x;
  const int u = t & 31;
  const int jp = t >> 5;                      // 0..7
  const int s = S0 + u;                       // residue (= col mod 128)
  const int j0 = jp << 1;
  const int w0 = (S0 + 125) & 127;            // (S0 - 3) mod 128
  const int res = (w0 + u) & 127;             // (s - 3) mod 128

  // 2x16 coefficients, i-aligned with off[] below.
  float mc0[16], mc1[16];
  {
    const float* r0p = mcl + ((s * 16 + j0) << 4);
#pragma unroll
    for (int i = 0; i < 16; ++i) { mc0[i] = r0p[i]; mc1[i] = r0p[16 + i]; }
  }

  // 16 x-column offsets (row-invariant): res + 128*i, never wraps.
  int off[16];
#pragma unroll
  for (int i = 0; i < 16; ++i) off[i] = res + (i << 7);

  const int c0 = s + (j0 << 7);
  const int c1 = c0 + 128;
  const float bi0 = bias[c0];
  const float bi1 = bias[c1];

  const float* xr0 = x + (size_t)b0 * NN;     // row b0
  float xa[16], xb[16];
#pragma unroll
  for (int i = 0; i < 16; ++i) xa[i] = xr0[off[i]];

  for (int r = 0; r < 32; r += 2) {
    const float* xcur = x + (size_t)(b0 + r) * NN;
    // issue row r+1 loads (in flight during row r compute)
#pragma unroll
    for (int i = 0; i < 16; ++i) xb[i] = xcur[NN + off[i]];
    {
      float acc0 = bi0, acc1 = bi1;
#pragma unroll
      for (int i = 0; i < 16; ++i) {
        acc0 = fmaf(xa[i], mc0[i], acc0);
        acc1 = fmaf(xa[i], mc1[i], acc1);
      }
      size_t ob = (size_t)(b0 + r) * NN;
      __builtin_nontemporal_store(fmaxf(acc0, 0.f), &out[ob + c0]);
      __builtin_nontemporal_store(fmaxf(acc1, 0.f), &out[ob + c1]);
    }
    // issue row r+2 loads (in flight during row r+1 compute)
    if (r + 2 < 32) {
#pragma unroll
      for (int i = 0; i < 16; ++i) xa[i] = xcur[2 * NN + off[i]];
    }
    {
      float acc0 = bi0, acc1 = bi1;
#pragma unroll
      for (int i = 0; i < 16; ++i) {
        acc0 = fmaf(xb[i], mc0[i], acc0);
        acc1 = fmaf(xb[i], mc1[i], acc1);
      }
      size_t ob = (size_t)(b0 + r + 1) * NN;
      __builtin_nontemporal_store(fmaxf(acc0, 0.f), &out[ob + c0]);
      __builtin_nontemporal_store(fmaxf(acc1, 0.f), &out[ob + c1]);
    }
  }
}

extern "C" void kernel_launch(void* const* d_in, const int* in_sizes, int n_in,
                              void* d_out, int out_size, void* d_ws, size_t ws_size,
                              hipStream_t stream) {
  // 0:x 1:vals0 2:vals1 3:vals2 4:rows0 5:cols0 6:rows1 7:cols1 8:rows2 9:cols2
  // 10:scaling 11:bias
  const float* x       = (const float*)d_in[0];
  const float* v0      = (const float*)d_in[1];
  const float* v1      = (const float*)d_in[2];
  const float* v2      = (const float*)d_in[3];
  const float* scaling = (const float*)d_in[10];
  const float* bias    = (const float*)d_in[11];
  float* out = (float*)d_out;

  float* w01 = (float*)d_ws;          // 2048*16 floats = 128 KiB
  float* mcl = w01 + NN * KK;         // 2048*16 floats = 128 KiB

  const int B = in_sizes[0] / NN;     // 16384

  hipLaunchKernelGGL(sfd_compose01, dim3(128), dim3(256), 0, stream, v0, v1, w01);
  hipLaunchKernelGGL(sfd_compose012, dim3(128), dim3(256), 0, stream, v2, w01, scaling, mcl);
  hipLaunchKernelGGL(sfd_apply, dim3(4, B >> 5), dim3(256), 0, stream, x, mcl, bias, out);
}